// Round 1
// baseline (1065.364 us; speedup 1.0000x reference)
//
#include <hip/hip_runtime.h>

#define NQ   65536
#define NC   4096
#define SOUT 64

// 1 thread = 1 query, 64 fp32 accumulators in registers.
// All 4096 centers staged once in LDS as float4(y0,y1,y2,|y|^2) = 64 KB.
// Coeff rows are wave-uniform per center -> scalar loads (SMEM pipe).
__launch_bounds__(256)
__global__ void rbf_tps_kernel(const float* __restrict__ x,
                               const float* __restrict__ y,
                               const float* __restrict__ coeffs,
                               const float* __restrict__ shift,
                               const float* __restrict__ scale,
                               float* __restrict__ out) {
    __shared__ float4 ytile[NC];  // 64 KB

    const int tid = threadIdx.x;

    // Stage centers into LDS with precomputed |y|^2.
    for (int j = tid; j < NC; j += 256) {
        const float y0 = y[j * 3 + 0];
        const float y1 = y[j * 3 + 1];
        const float y2 = y[j * 3 + 2];
        ytile[j] = make_float4(y0, y1, y2, y0 * y0 + y1 * y1 + y2 * y2);
    }
    __syncthreads();

    const int q = blockIdx.x * 256 + tid;
    const float x0 = x[q * 3 + 0];
    const float x1 = x[q * 3 + 1];
    const float x2 = x[q * 3 + 2];
    const float xsq = x0 * x0 + x1 * x1 + x2 * x2;

    // Polynomial part: monomial order from combinations_with_replacement:
    // [1, xh0, xh1, xh2]  (DEGREE=1, NDIM=3)
    const float sh0 = shift[0], sh1 = shift[1], sh2 = shift[2];
    const float sc0 = scale[0], sc1 = scale[1], sc2 = scale[2];
    const float xh0 = (x0 - sh0) / sc0;
    const float xh1 = (x1 - sh1) / sc1;
    const float xh2 = (x2 - sh2) / sc2;

    float acc[SOUT];
    {
        const float* c0 = &coeffs[(size_t)(NC + 0) * SOUT];
        const float* c1 = &coeffs[(size_t)(NC + 1) * SOUT];
        const float* c2 = &coeffs[(size_t)(NC + 2) * SOUT];
        const float* c3 = &coeffs[(size_t)(NC + 3) * SOUT];
        #pragma unroll
        for (int s = 0; s < SOUT; ++s) {
            acc[s] = c0[s] + xh0 * c1[s] + xh1 * c2[s] + xh2 * c3[s];
        }
    }

    // Main loop over all centers. No barriers inside.
    #pragma unroll 2
    for (int j = 0; j < NC; ++j) {
        const float4 yj = ytile[j];
        const float dot = x0 * yj.x + x1 * yj.y + x2 * yj.z;
        float r2 = fmaf(-2.0f, dot, xsq + yj.w);
        r2 = fmaxf(r2, 0.0f);
        // f(r) = r^2 log(r) = 0.5 * r2 * log(r2); f(0)=0.
        // max(r2,1e-37): at r2==0 gives 0 * log(1e-37) = 0 (finite), no NaN.
        const float f = 0.5f * r2 * __logf(fmaxf(r2, 1e-37f));
        const float* __restrict__ cj = &coeffs[(size_t)j * SOUT];
        #pragma unroll
        for (int s = 0; s < SOUT; ++s) {
            acc[s] = fmaf(f, cj[s], acc[s]);
        }
    }

    // Write 64 contiguous floats per query.
    float4* o4 = (float4*)&out[(size_t)q * SOUT];
    #pragma unroll
    for (int s = 0; s < SOUT / 4; ++s) {
        o4[s] = make_float4(acc[4 * s + 0], acc[4 * s + 1],
                            acc[4 * s + 2], acc[4 * s + 3]);
    }
}

extern "C" void kernel_launch(void* const* d_in, const int* in_sizes, int n_in,
                              void* d_out, int out_size, void* d_ws, size_t ws_size,
                              hipStream_t stream) {
    const float* x      = (const float*)d_in[0];
    const float* y      = (const float*)d_in[1];
    const float* coeffs = (const float*)d_in[2];
    const float* shift  = (const float*)d_in[3];
    const float* scale  = (const float*)d_in[4];
    // d_in[5] = powers (int32) — monomial order hardcoded for DEGREE=1/NDIM=3.
    float* out = (float*)d_out;

    dim3 grid(NQ / 256);
    dim3 block(256);
    hipLaunchKernelGGL(rbf_tps_kernel, grid, block, 0, stream,
                       x, y, coeffs, shift, scale, out);
}

// Round 2
// 304.638 us; speedup vs baseline: 3.4972x; 3.4972x over previous
//
#include <hip/hip_runtime.h>

#define NQ   65536
#define NC   4096
#define SOUT 64
#define NR   4                 // monomials (DEGREE=1, NDIM=3)
#define KTOT (NC + 64)         // 4160: K padded so poly rides the last chunk
#define BM   128
#define BK   64
#define NCH  (KTOT / BK)       // 65 chunks
#define SA   72                // A_lds row stride in bf16 (64 + 8 pad -> 2-way banks, free)

typedef float f32x4 __attribute__((ext_vector_type(4)));
typedef short short8 __attribute__((ext_vector_type(8)));

// ---------------- pre-kernels (write d_ws; run every call, deterministic) -----

// Bt[n][k] = bf16(coeffs[k][n]) for k < NC+NR, else 0.  (64 x 4160)
__global__ void prep_bt(const float* __restrict__ coeffs, __bf16* __restrict__ bt) {
    const int k = blockIdx.x * 256 + threadIdx.x;
    const int n = blockIdx.y;
    if (k >= KTOT) return;
    const float v = (k < NC + NR) ? coeffs[(size_t)k * SOUT + n] : 0.0f;
    bt[(size_t)n * KTOT + k] = (__bf16)v;
}

// y4[k] = (y0, y1, y2, |y|^2)
__global__ void prep_y4(const float* __restrict__ y, float4* __restrict__ y4) {
    const int k = blockIdx.x * 256 + threadIdx.x;
    if (k >= NC) return;
    const float a = y[k * 3 + 0], b = y[k * 3 + 1], c = y[k * 3 + 2];
    y4[k] = make_float4(a, b, c, a * a + b * b + c * c);
}

// ---------------- main MFMA kernel -------------------------------------------
// Block: 256 threads = 4 waves (2x2), tile BM=128 x SOUT=64, K-chunks of 64.
// A (f-values) computed in-regs -> bf16 -> padded LDS; B frags straight from
// global Bt (L2-hot, issued before the eval phase so latency hides under VALU).
__launch_bounds__(256)
__global__ void rbf_mfma(const float* __restrict__ x,
                         const float4* __restrict__ y4,
                         const float* __restrict__ shift,
                         const float* __restrict__ scale,
                         const __bf16* __restrict__ bt,
                         float* __restrict__ out) {
    __shared__ __bf16 A_lds[BM * SA];   // 18,432 B

    const int t    = threadIdx.x;
    const int wave = t >> 6;
    const int lane = t & 63;
    const int q0   = blockIdx.x * BM;

    // eval-phase identity: thread owns one query row, half the k-chunk
    const int tm = t & 127;            // query row within tile
    const int th = t >> 7;             // 0: k 0..31, 1: k 32..63
    const int q  = q0 + tm;

    const float x0 = x[q * 3 + 0];
    const float x1 = x[q * 3 + 1];
    const float x2 = x[q * 3 + 2];
    const float xsq = x0 * x0 + x1 * x1 + x2 * x2;

    const float xh0 = (x0 - shift[0]) / scale[0];
    const float xh1 = (x1 - shift[1]) / scale[1];
    const float xh2 = (x2 - shift[2]) / scale[2];

    // mfma-phase identity
    const int wm  = wave >> 1;         // m offset wm*64
    const int wn  = wave & 1;          // n offset wn*32
    const int l15 = lane & 15;
    const int lg  = lane >> 4;

    f32x4 acc[4][2] = {};              // [mf][nf]

    for (int ch = 0; ch < NCH; ++ch) {
        const int k0 = ch * BK;

        // ---- issue B-fragment loads early (global, L2-resident) ----
        short8 bfrag[2][2];            // [nf][kk]
        #pragma unroll
        for (int nf = 0; nf < 2; ++nf) {
            #pragma unroll
            for (int kk = 0; kk < 2; ++kk) {
                const int n  = wn * 32 + nf * 16 + l15;
                const int kb = k0 + kk * 32 + lg * 8;
                bfrag[nf][kk] = *(const short8*)(bt + (size_t)n * KTOT + kb);
            }
        }

        __syncthreads();   // previous iteration done reading A_lds

        // ---- compute A tile -> LDS (bf16, padded rows) ----
        const int kbase = k0 + th * 32;
        #pragma unroll 2
        for (int j = 0; j < 4; ++j) {          // 4 x short8 per thread
            short8 pk;
            #pragma unroll
            for (int i2 = 0; i2 < 8; ++i2) {
                const int kc = kbase + j * 8 + i2;   // global k index
                float fv;
                if (ch == NCH - 1) {
                    // poly chunk: A = [1, xh0, xh1, xh2, 0...]
                    const int kl = th * 32 + j * 8 + i2;
                    fv = (kl == 0) ? 1.0f :
                         (kl == 1) ? xh0  :
                         (kl == 2) ? xh1  :
                         (kl == 3) ? xh2  : 0.0f;
                } else {
                    const float4 yv = y4[kc];
                    float dot = x0 * yv.x;
                    dot = fmaf(x1, yv.y, dot);
                    dot = fmaf(x2, yv.z, dot);
                    const float r2 = fmaf(-2.0f, dot, xsq + yv.w);
                    // f = 0.5*r2*ln(r2) = 0.34657359 * r2 * log2(r2); f(<=0)=~0
                    const float lg2 = __log2f(fmaxf(r2, 1e-37f));
                    fv = r2 * (0.34657359f * lg2);
                }
                pk[i2] = __builtin_bit_cast(short, (__bf16)fv);
            }
            *(short8*)(&A_lds[tm * SA + th * 32 + j * 8]) = pk;
        }

        __syncthreads();   // A tile ready

        // ---- MFMA: 16 per wave per chunk ----
        #pragma unroll
        for (int kk = 0; kk < 2; ++kk) {
            #pragma unroll
            for (int mf = 0; mf < 4; ++mf) {
                const int m  = wm * 64 + mf * 16 + l15;
                const int ke = kk * 32 + lg * 8;
                const short8 af = *(const short8*)(&A_lds[m * SA + ke]);
                #pragma unroll
                for (int nf = 0; nf < 2; ++nf) {
                    acc[mf][nf] = __builtin_amdgcn_mfma_f32_16x16x32_bf16(
                        af, bfrag[nf][kk], acc[mf][nf], 0, 0, 0);
                }
            }
        }
    }

    // ---- epilogue: C/D layout col=lane&15, row=(lane>>4)*4+reg (m89) ----
    #pragma unroll
    for (int mf = 0; mf < 4; ++mf) {
        #pragma unroll
        for (int nf = 0; nf < 2; ++nf) {
            #pragma unroll
            for (int r = 0; r < 4; ++r) {
                const int m = wm * 64 + mf * 16 + lg * 4 + r;
                const int n = wn * 32 + nf * 16 + l15;
                out[(size_t)(q0 + m) * SOUT + n] = acc[mf][nf][r];
            }
        }
    }
}

// ---------------- fallback (round-1 kernel) if d_ws is too small -------------
__launch_bounds__(256)
__global__ void rbf_tps_fallback(const float* __restrict__ x,
                                 const float* __restrict__ y,
                                 const float* __restrict__ coeffs,
                                 const float* __restrict__ shift,
                                 const float* __restrict__ scale,
                                 float* __restrict__ out) {
    __shared__ float4 ytile[NC];
    const int tid = threadIdx.x;
    for (int j = tid; j < NC; j += 256) {
        const float a = y[j * 3], b = y[j * 3 + 1], c = y[j * 3 + 2];
        ytile[j] = make_float4(a, b, c, a * a + b * b + c * c);
    }
    __syncthreads();
    const int q = blockIdx.x * 256 + tid;
    const float x0 = x[q * 3], x1 = x[q * 3 + 1], x2 = x[q * 3 + 2];
    const float xsq = x0 * x0 + x1 * x1 + x2 * x2;
    const float xh0 = (x0 - shift[0]) / scale[0];
    const float xh1 = (x1 - shift[1]) / scale[1];
    const float xh2 = (x2 - shift[2]) / scale[2];
    float acc[SOUT];
    {
        const float* c0 = &coeffs[(size_t)(NC + 0) * SOUT];
        const float* c1 = &coeffs[(size_t)(NC + 1) * SOUT];
        const float* c2 = &coeffs[(size_t)(NC + 2) * SOUT];
        const float* c3 = &coeffs[(size_t)(NC + 3) * SOUT];
        #pragma unroll
        for (int s = 0; s < SOUT; ++s)
            acc[s] = c0[s] + xh0 * c1[s] + xh1 * c2[s] + xh2 * c3[s];
    }
    #pragma unroll 2
    for (int j = 0; j < NC; ++j) {
        const float4 yj = ytile[j];
        const float dot = x0 * yj.x + x1 * yj.y + x2 * yj.z;
        float r2 = fmaf(-2.0f, dot, xsq + yj.w);
        r2 = fmaxf(r2, 0.0f);
        const float f = 0.5f * r2 * __logf(fmaxf(r2, 1e-37f));
        const float* __restrict__ cj = &coeffs[(size_t)j * SOUT];
        #pragma unroll
        for (int s = 0; s < SOUT; ++s) acc[s] = fmaf(f, cj[s], acc[s]);
    }
    float4* o4 = (float4*)&out[(size_t)q * SOUT];
    #pragma unroll
    for (int s = 0; s < SOUT / 4; ++s)
        o4[s] = make_float4(acc[4 * s], acc[4 * s + 1], acc[4 * s + 2], acc[4 * s + 3]);
}

extern "C" void kernel_launch(void* const* d_in, const int* in_sizes, int n_in,
                              void* d_out, int out_size, void* d_ws, size_t ws_size,
                              hipStream_t stream) {
    const float* x      = (const float*)d_in[0];
    const float* y      = (const float*)d_in[1];
    const float* coeffs = (const float*)d_in[2];
    const float* shift  = (const float*)d_in[3];
    const float* scale  = (const float*)d_in[4];
    float* out = (float*)d_out;

    const size_t bt_bytes = (size_t)SOUT * KTOT * sizeof(short);  // 532,480
    const size_t y4_bytes = (size_t)NC * sizeof(float4);          //  65,536

    if (ws_size >= bt_bytes + y4_bytes) {
        __bf16* bt = (__bf16*)d_ws;
        float4* y4 = (float4*)((char*)d_ws + bt_bytes);
        hipLaunchKernelGGL(prep_bt, dim3((KTOT + 255) / 256, SOUT), dim3(256),
                           0, stream, coeffs, bt);
        hipLaunchKernelGGL(prep_y4, dim3((NC + 255) / 256), dim3(256),
                           0, stream, y, y4);
        hipLaunchKernelGGL(rbf_mfma, dim3(NQ / BM), dim3(256), 0, stream,
                           x, y4, shift, scale, bt, out);
    } else {
        hipLaunchKernelGGL(rbf_tps_fallback, dim3(NQ / 256), dim3(256),
                           0, stream, x, y, coeffs, shift, scale, out);
    }
}

// Round 4
// 174.570 us; speedup vs baseline: 6.1028x; 1.7451x over previous
//
#include <hip/hip_runtime.h>

#define NQ   65536
#define NC   4096
#define SOUT 64
#define NR   4                 // monomials (DEGREE=1, NDIM=3)
#define KTOT (NC + 64)         // 4160: K padded so poly rides the last chunk
#define BM   128
#define BK   64
#define NCH2 (NC / BK)         // 64 r2 chunks; chunk 64 = poly

typedef float    f32x4 __attribute__((ext_vector_type(4)));
typedef _Float16 f16x8 __attribute__((ext_vector_type(8)));
typedef __fp16   h16x2 __attribute__((ext_vector_type(2)));  // cvt_pkrtz native type

// ---------------- pre-kernels (write d_ws; deterministic every call) ---------

// Bt[n][k] = f16(coeffs[k][n]) for k < NC+NR, else 0.  (64 x 4160)
__global__ void prep_bt(const float* __restrict__ coeffs, _Float16* __restrict__ bt) {
    const int k = blockIdx.x * 256 + threadIdx.x;
    const int n = blockIdx.y;
    if (k >= KTOT) return;
    const float v = (k < NC + NR) ? coeffs[(size_t)k * SOUT + n] : 0.0f;
    bt[(size_t)n * KTOT + k] = (_Float16)v;
}

// Ye[k] = [-2y0, -2y1, -2y2, 1, |y|^2, 0,0,0]  (f16, 16 B rows)
__global__ void prep_ye(const float* __restrict__ y, _Float16* __restrict__ ye) {
    const int k = blockIdx.x * 256 + threadIdx.x;
    if (k >= NC) return;
    const float a = y[k * 3 + 0], b = y[k * 3 + 1], c = y[k * 3 + 2];
    const float s = a * a + b * b + c * c;
    f16x8 r = {(_Float16)(-2.0f * a), (_Float16)(-2.0f * b), (_Float16)(-2.0f * c),
               (_Float16)1.0f, (_Float16)s,
               (_Float16)0.0f, (_Float16)0.0f, (_Float16)0.0f};
    *(f16x8*)(ye + (size_t)k * 8) = r;
}

// ---------------- main kernel ------------------------------------------------
// Block 256 = 4 waves. Tile BM=128 x SOUT=64, K-chunks of 64.
// Phase 1: r2 tiles via mfma(A=Ye, B=Xe) -> lane holds 4 consecutive k per q.
// Phase 2: f = 0.34657*r2*log2(r2) in-reg, cvt_pkrtz -> ds_write_b64 to A_lds
//          ([128][64] f16, XOR-swizzled: byte ^= (row&7)<<4).
// Phase 3: ds_read_b128 A-frags + mfma against Bt frags (global, L2-hot).
__launch_bounds__(256)
__global__ void rbf_mfma2(const float* __restrict__ x,
                          const _Float16* __restrict__ ye,
                          const float* __restrict__ shift,
                          const float* __restrict__ scale,
                          const _Float16* __restrict__ bt,
                          float* __restrict__ out) {
    __shared__ __align__(16) char A_lds[BM * 128];   // 16 KB, f16 [128][64] swizzled

    const int t    = threadIdx.x;
    const int wave = t >> 6;
    const int lane = t & 63;
    const int l15  = lane & 15;
    const int lg   = lane >> 4;
    const int q0   = blockIdx.x * BM;

    // out-GEMM wave tiling (2x2): m-offset wm*64, n-offset wn*32
    const int wm = wave >> 1;
    const int wn = wave & 1;

    // phase-1: wave owns q rows [wave*32, wave*32+32)
    const int wq = wave * 32;

    // Xe B-fragments (once): lg==0 lanes hold [x0,x1,x2,xsq,1,0,0,0], else 0
    f16x8 xef[2];
    #pragma unroll
    for (int qt = 0; qt < 2; ++qt) {
        f16x8 v = {};
        if (lg == 0) {
            const int q = q0 + wq + qt * 16 + l15;
            const float a = x[q * 3 + 0], b = x[q * 3 + 1], c = x[q * 3 + 2];
            const float s = a * a + b * b + c * c;
            v[0] = (_Float16)a; v[1] = (_Float16)b; v[2] = (_Float16)c;
            v[3] = (_Float16)s; v[4] = (_Float16)1.0f;
        }
        xef[qt] = v;
    }

    // poly row values for this thread's A-row (used in the last chunk)
    const int tm = t & 127;
    const int th = t >> 7;
    uint2 poly01;   // f16x4 {1, xh0, xh1, xh2}
    {
        const int q = q0 + tm;
        const float a = x[q * 3 + 0], b = x[q * 3 + 1], c = x[q * 3 + 2];
        const float xh0 = (a - shift[0]) / scale[0];
        const float xh1 = (b - shift[1]) / scale[1];
        const float xh2 = (c - shift[2]) / scale[2];
        h16x2 p0 = __builtin_amdgcn_cvt_pkrtz(1.0f, xh0);
        h16x2 p1 = __builtin_amdgcn_cvt_pkrtz(xh1, xh2);
        poly01.x = __builtin_bit_cast(unsigned, p0);
        poly01.y = __builtin_bit_cast(unsigned, p1);
    }

    f32x4 acc[4][2] = {};   // [mf][nf]

    for (int ch = 0; ch <= NCH2; ++ch) {
        const int k0 = ch * BK;

        // ---- B fragments for the out-GEMM (issue early; L2-resident) ----
        f16x8 bfrag[2][2];
        #pragma unroll
        for (int nf = 0; nf < 2; ++nf)
            #pragma unroll
            for (int kk = 0; kk < 2; ++kk) {
                const int n  = wn * 32 + nf * 16 + l15;
                const int kb = k0 + kk * 32 + lg * 8;
                bfrag[nf][kk] = *(const f16x8*)(bt + (size_t)n * KTOT + kb);
            }

        if (ch < NCH2) {
            // ---- phase 1: r2 tiles. Ye A-frags: broadcast rows, no predication
            f32x4 r2a[2][4];
            #pragma unroll
            for (int kt = 0; kt < 4; ++kt) {
                const f16x8 yef = *(const f16x8*)(ye + (size_t)(k0 + kt * 16 + l15) * 8);
                #pragma unroll
                for (int qt = 0; qt < 2; ++qt) {
                    f32x4 z = {};
                    r2a[qt][kt] = __builtin_amdgcn_mfma_f32_16x16x32_f16(
                        yef, xef[qt], z, 0, 0, 0);
                }
            }

            __syncthreads();   // all waves done reading A_lds (prev chunk)

            // ---- phase 2: f-eval + pack + swizzled b64 writes ----
            #pragma unroll
            for (int qt = 0; qt < 2; ++qt) {
                const int row = wq + qt * 16 + l15;
                const int rswz = (row & 7) << 4;
                #pragma unroll
                for (int kt = 0; kt < 4; ++kt) {
                    float f[4];
                    #pragma unroll
                    for (int r = 0; r < 4; ++r) {
                        const float rc = fmaxf(r2a[qt][kt][r], 1e-37f);
                        f[r] = 0.34657359f * rc * __log2f(rc);
                    }
                    h16x2 h0 = __builtin_amdgcn_cvt_pkrtz(f[0], f[1]);
                    h16x2 h1 = __builtin_amdgcn_cvt_pkrtz(f[2], f[3]);
                    uint2 w;
                    w.x = __builtin_bit_cast(unsigned, h0);
                    w.y = __builtin_bit_cast(unsigned, h1);
                    const int colb = kt * 32 + lg * 8;   // k = kt*16 + lg*4, f16->bytes
                    *(uint2*)(&A_lds[row * 128 + (colb ^ rswz)]) = w;
                }
            }
        } else {
            __syncthreads();
            // ---- poly chunk: A = [1, xh0, xh1, xh2, 0...] ----
            const int row = tm;
            const int rswz = (row & 7) << 4;
            #pragma unroll
            for (int j = 0; j < 8; ++j) {
                const int colb = th * 64 + j * 8;
                uint2 w = (th == 0 && j == 0) ? poly01 : make_uint2(0u, 0u);
                *(uint2*)(&A_lds[row * 128 + (colb ^ rswz)]) = w;
            }
        }

        __syncthreads();   // A tile ready

        // ---- phase 3: out-GEMM MFMAs ----
        #pragma unroll
        for (int kk = 0; kk < 2; ++kk)
            #pragma unroll
            for (int mf = 0; mf < 4; ++mf) {
                const int m = wm * 64 + mf * 16 + l15;
                const int colb = kk * 64 + lg * 16;   // ke = kk*32 + lg*8, bytes
                const f16x8 af = *(const f16x8*)(
                    &A_lds[m * 128 + (colb ^ ((m & 7) << 4))]);
                #pragma unroll
                for (int nf = 0; nf < 2; ++nf)
                    acc[mf][nf] = __builtin_amdgcn_mfma_f32_16x16x32_f16(
                        af, bfrag[nf][kk], acc[mf][nf], 0, 0, 0);
            }
    }

    // ---- epilogue: C/D layout col=lane&15, row=(lane>>4)*4+reg ----
    #pragma unroll
    for (int mf = 0; mf < 4; ++mf)
        #pragma unroll
        for (int nf = 0; nf < 2; ++nf)
            #pragma unroll
            for (int r = 0; r < 4; ++r) {
                const int m = wm * 64 + mf * 16 + lg * 4 + r;
                const int n = wn * 32 + nf * 16 + l15;
                out[(size_t)(q0 + m) * SOUT + n] = acc[mf][nf][r];
            }
}

// ---------------- fallback (round-1 kernel) if d_ws too small ----------------
__launch_bounds__(256)
__global__ void rbf_tps_fallback(const float* __restrict__ x,
                                 const float* __restrict__ y,
                                 const float* __restrict__ coeffs,
                                 const float* __restrict__ shift,
                                 const float* __restrict__ scale,
                                 float* __restrict__ out) {
    __shared__ float4 ytile[NC];
    const int tid = threadIdx.x;
    for (int j = tid; j < NC; j += 256) {
        const float a = y[j * 3], b = y[j * 3 + 1], c = y[j * 3 + 2];
        ytile[j] = make_float4(a, b, c, a * a + b * b + c * c);
    }
    __syncthreads();
    const int q = blockIdx.x * 256 + tid;
    const float x0 = x[q * 3], x1 = x[q * 3 + 1], x2 = x[q * 3 + 2];
    const float xsq = x0 * x0 + x1 * x1 + x2 * x2;
    const float xh0 = (x0 - shift[0]) / scale[0];
    const float xh1 = (x1 - shift[1]) / scale[1];
    const float xh2 = (x2 - shift[2]) / scale[2];
    float acc[SOUT];
    {
        const float* c0 = &coeffs[(size_t)(NC + 0) * SOUT];
        const float* c1 = &coeffs[(size_t)(NC + 1) * SOUT];
        const float* c2 = &coeffs[(size_t)(NC + 2) * SOUT];
        const float* c3 = &coeffs[(size_t)(NC + 3) * SOUT];
        #pragma unroll
        for (int s = 0; s < SOUT; ++s)
            acc[s] = c0[s] + xh0 * c1[s] + xh1 * c2[s] + xh2 * c3[s];
    }
    #pragma unroll 2
    for (int j = 0; j < NC; ++j) {
        const float4 yj = ytile[j];
        const float dot = x0 * yj.x + x1 * yj.y + x2 * yj.z;
        float r2 = fmaf(-2.0f, dot, xsq + yj.w);
        r2 = fmaxf(r2, 0.0f);
        const float f = 0.5f * r2 * __logf(fmaxf(r2, 1e-37f));
        const float* __restrict__ cj = &coeffs[(size_t)j * SOUT];
        #pragma unroll
        for (int s = 0; s < SOUT; ++s) acc[s] = fmaf(f, cj[s], acc[s]);
    }
    float4* o4 = (float4*)&out[(size_t)q * SOUT];
    #pragma unroll
    for (int s = 0; s < SOUT / 4; ++s)
        o4[s] = make_float4(acc[4 * s], acc[4 * s + 1], acc[4 * s + 2], acc[4 * s + 3]);
}

extern "C" void kernel_launch(void* const* d_in, const int* in_sizes, int n_in,
                              void* d_out, int out_size, void* d_ws, size_t ws_size,
                              hipStream_t stream) {
    const float* x      = (const float*)d_in[0];
    const float* y      = (const float*)d_in[1];
    const float* coeffs = (const float*)d_in[2];
    const float* shift  = (const float*)d_in[3];
    const float* scale  = (const float*)d_in[4];
    float* out = (float*)d_out;

    const size_t bt_bytes = (size_t)SOUT * KTOT * sizeof(_Float16);  // 532,480
    const size_t ye_bytes = (size_t)NC * 8 * sizeof(_Float16);       //  65,536

    if (ws_size >= bt_bytes + ye_bytes) {
        _Float16* bt = (_Float16*)d_ws;
        _Float16* yep = (_Float16*)((char*)d_ws + bt_bytes);
        hipLaunchKernelGGL(prep_bt, dim3((KTOT + 255) / 256, SOUT), dim3(256),
                           0, stream, coeffs, bt);
        hipLaunchKernelGGL(prep_ye, dim3((NC + 255) / 256), dim3(256),
                           0, stream, y, yep);
        hipLaunchKernelGGL(rbf_mfma2, dim3(NQ / BM), dim3(256), 0, stream,
                           x, yep, shift, scale, bt, out);
    } else {
        hipLaunchKernelGGL(rbf_tps_fallback, dim3(NQ / 256), dim3(256),
                           0, stream, x, y, coeffs, shift, scale, out);
    }
}

// Round 5
// 157.482 us; speedup vs baseline: 6.7650x; 1.1085x over previous
//
#include <hip/hip_runtime.h>

#define NQ   65536
#define NC   4096
#define SOUT 64
#define NR   4                 // monomials (DEGREE=1, NDIM=3)
#define KTOT (NC + 64)         // 4160: K padded so poly rides the last chunk
#define BM   64
#define BK   64
#define NCH2 (NC / BK)         // 64 r2 chunks; chunk 64 = poly

typedef float    f32x4 __attribute__((ext_vector_type(4)));
typedef _Float16 f16x8 __attribute__((ext_vector_type(8)));
typedef __fp16   h16x2 __attribute__((ext_vector_type(2)));  // cvt_pkrtz native type

// ---------------- pre-kernels (write d_ws; deterministic every call) ---------

// Bt[n][k] = f16(coeffs[k][n]) for k < NC+NR, else 0.  (64 x 4160)
__global__ void prep_bt(const float* __restrict__ coeffs, _Float16* __restrict__ bt) {
    const int k = blockIdx.x * 256 + threadIdx.x;
    const int n = blockIdx.y;
    if (k >= KTOT) return;
    const float v = (k < NC + NR) ? coeffs[(size_t)k * SOUT + n] : 0.0f;
    bt[(size_t)n * KTOT + k] = (_Float16)v;
}

// Ye[k] = [-2y0, -2y1, -2y2, 1, |y|^2, 0,0,0]  (f16, 16 B rows)
__global__ void prep_ye(const float* __restrict__ y, _Float16* __restrict__ ye) {
    const int k = blockIdx.x * 256 + threadIdx.x;
    if (k >= NC) return;
    const float a = y[k * 3 + 0], b = y[k * 3 + 1], c = y[k * 3 + 2];
    const float s = a * a + b * b + c * c;
    f16x8 r = {(_Float16)(-2.0f * a), (_Float16)(-2.0f * b), (_Float16)(-2.0f * c),
               (_Float16)1.0f, (_Float16)s,
               (_Float16)0.0f, (_Float16)0.0f, (_Float16)0.0f};
    *(f16x8*)(ye + (size_t)k * 8) = r;
}

// ---------------- main kernel ------------------------------------------------
// Block 256 = 4 waves. Tile BM=64 x SOUT=64 (grid 1024 -> 4 blocks/CU).
// Double-buffered A_lds: iteration ch reads buf[ch&1] (out-GEMM) while
// computing chunk ch+1 (r2-MFMA -> f-eval -> swizzled write) into buf[~].
// One barrier per chunk.
__launch_bounds__(256)
__global__ void rbf_mfma3(const float* __restrict__ x,
                          const _Float16* __restrict__ ye,
                          const float* __restrict__ shift,
                          const float* __restrict__ scale,
                          const _Float16* __restrict__ bt,
                          float* __restrict__ out) {
    __shared__ __align__(16) char A_lds[2][BM * 128];   // 2 x 8 KB

    const int t    = threadIdx.x;
    const int wave = t >> 6;
    const int lane = t & 63;
    const int l15  = lane & 15;
    const int lg   = lane >> 4;
    const int q0   = blockIdx.x * BM;

    // out-GEMM wave tiling (2x2): m-offset wm*32, n-offset wn*32
    const int wm = wave >> 1;
    const int wn = wave & 1;

    // phase-1/2: wave owns q rows [wave*16, wave*16+16)
    const int wq = wave * 16;

    // Xe B-fragment: lg==0 lanes hold [x0,x1,x2,xsq,1,0,0,0], else 0
    f16x8 xef = {};
    if (lg == 0) {
        const int q = q0 + wq + l15;
        const float a = x[q * 3 + 0], b = x[q * 3 + 1], c = x[q * 3 + 2];
        xef[0] = (_Float16)a; xef[1] = (_Float16)b; xef[2] = (_Float16)c;
        xef[3] = (_Float16)(a * a + b * b + c * c); xef[4] = (_Float16)1.0f;
    }

    // poly row values (chunk 64): row tm = t&63, 4 threads th=0..3 cover 128 B
    const int tm = t & 63;
    const int th = t >> 6;
    uint2 poly01;   // f16x4 {1, xh0, xh1, xh2}
    {
        const int q = q0 + tm;
        const float a = x[q * 3 + 0], b = x[q * 3 + 1], c = x[q * 3 + 2];
        h16x2 p0 = __builtin_amdgcn_cvt_pkrtz(1.0f, (a - shift[0]) / scale[0]);
        h16x2 p1 = __builtin_amdgcn_cvt_pkrtz((b - shift[1]) / scale[1],
                                              (c - shift[2]) / scale[2]);
        poly01.x = __builtin_bit_cast(unsigned, p0);
        poly01.y = __builtin_bit_cast(unsigned, p1);
    }

    f32x4 acc[2][2] = {};   // [mf][nf]

    // compute chunk c (r2 -> f16 f-values, or poly) into buf
    auto compute_chunk = [&](int c, char* buf) {
        if (c < NCH2) {
            const int k0   = c * BK;
            const int row  = wq + l15;
            const int rswz = (row & 7) << 4;
            #pragma unroll
            for (int kt = 0; kt < 4; ++kt) {
                const f16x8 yef = *(const f16x8*)(ye + (size_t)(k0 + kt * 16 + l15) * 8);
                f32x4 z = {};
                const f32x4 r2 = __builtin_amdgcn_mfma_f32_16x16x32_f16(
                    yef, xef, z, 0, 0, 0);
                float f[4];
                #pragma unroll
                for (int r = 0; r < 4; ++r) {
                    const float rc = fmaxf(r2[r], 1e-37f);
                    f[r] = 0.34657359f * rc * __log2f(rc);
                }
                h16x2 h0 = __builtin_amdgcn_cvt_pkrtz(f[0], f[1]);
                h16x2 h1 = __builtin_amdgcn_cvt_pkrtz(f[2], f[3]);
                uint2 w;
                w.x = __builtin_bit_cast(unsigned, h0);
                w.y = __builtin_bit_cast(unsigned, h1);
                const int colb = kt * 32 + lg * 8;   // k = kt*16 + lg*4
                *(uint2*)(&buf[row * 128 + (colb ^ rswz)]) = w;
            }
        } else {
            // poly chunk: A = [1, xh0, xh1, xh2, 0...]
            const int row  = tm;
            const int rswz = (row & 7) << 4;
            #pragma unroll
            for (int j = 0; j < 4; ++j) {
                const int colb = th * 32 + j * 8;
                uint2 w = (th == 0 && j == 0) ? poly01 : make_uint2(0u, 0u);
                *(uint2*)(&buf[row * 128 + (colb ^ rswz)]) = w;
            }
        }
    };

    compute_chunk(0, A_lds[0]);
    __syncthreads();

    for (int ch = 0; ch <= NCH2; ++ch) {
        const char* rbuf = A_lds[ch & 1];

        // B fragments for chunk ch (global, L2-hot; issued first)
        f16x8 bfrag[2][2];   // [nf][kk]
        #pragma unroll
        for (int nf = 0; nf < 2; ++nf)
            #pragma unroll
            for (int kk = 0; kk < 2; ++kk)
                bfrag[nf][kk] = *(const f16x8*)(
                    bt + (size_t)(wn * 32 + nf * 16 + l15) * KTOT
                       + ch * BK + kk * 32 + lg * 8);

        // A fragments for chunk ch (ds_read early; latency hides under compute)
        f16x8 af[2][2];      // [kk][mf]
        #pragma unroll
        for (int kk = 0; kk < 2; ++kk)
            #pragma unroll
            for (int mf = 0; mf < 2; ++mf) {
                const int m = wm * 32 + mf * 16 + l15;
                af[kk][mf] = *(const f16x8*)(
                    &rbuf[m * 128 + ((kk * 64 + lg * 16) ^ ((m & 7) << 4))]);
            }

        // compute next chunk into the other buffer (independent of reads)
        if (ch < NCH2) compute_chunk(ch + 1, A_lds[(ch + 1) & 1]);

        // out-GEMM MFMAs for chunk ch
        #pragma unroll
        for (int kk = 0; kk < 2; ++kk)
            #pragma unroll
            for (int mf = 0; mf < 2; ++mf)
                #pragma unroll
                for (int nf = 0; nf < 2; ++nf)
                    acc[mf][nf] = __builtin_amdgcn_mfma_f32_16x16x32_f16(
                        af[kk][mf], bfrag[nf][kk], acc[mf][nf], 0, 0, 0);

        __syncthreads();
    }

    // ---- epilogue: C/D layout col=lane&15, row=(lane>>4)*4+reg ----
    #pragma unroll
    for (int mf = 0; mf < 2; ++mf)
        #pragma unroll
        for (int nf = 0; nf < 2; ++nf)
            #pragma unroll
            for (int r = 0; r < 4; ++r) {
                const int m = wm * 32 + mf * 16 + lg * 4 + r;
                const int n = wn * 32 + nf * 16 + l15;
                out[(size_t)(q0 + m) * SOUT + n] = acc[mf][nf][r];
            }
}

// ---------------- fallback (round-1 kernel) if d_ws too small ----------------
__launch_bounds__(256)
__global__ void rbf_tps_fallback(const float* __restrict__ x,
                                 const float* __restrict__ y,
                                 const float* __restrict__ coeffs,
                                 const float* __restrict__ shift,
                                 const float* __restrict__ scale,
                                 float* __restrict__ out) {
    __shared__ float4 ytile[NC];
    const int tid = threadIdx.x;
    for (int j = tid; j < NC; j += 256) {
        const float a = y[j * 3], b = y[j * 3 + 1], c = y[j * 3 + 2];
        ytile[j] = make_float4(a, b, c, a * a + b * b + c * c);
    }
    __syncthreads();
    const int q = blockIdx.x * 256 + tid;
    const float x0 = x[q * 3], x1 = x[q * 3 + 1], x2 = x[q * 3 + 2];
    const float xsq = x0 * x0 + x1 * x1 + x2 * x2;
    const float xh0 = (x0 - shift[0]) / scale[0];
    const float xh1 = (x1 - shift[1]) / scale[1];
    const float xh2 = (x2 - shift[2]) / scale[2];
    float acc[SOUT];
    {
        const float* c0 = &coeffs[(size_t)(NC + 0) * SOUT];
        const float* c1 = &coeffs[(size_t)(NC + 1) * SOUT];
        const float* c2 = &coeffs[(size_t)(NC + 2) * SOUT];
        const float* c3 = &coeffs[(size_t)(NC + 3) * SOUT];
        #pragma unroll
        for (int s = 0; s < SOUT; ++s)
            acc[s] = c0[s] + xh0 * c1[s] + xh1 * c2[s] + xh2 * c3[s];
    }
    #pragma unroll 2
    for (int j = 0; j < NC; ++j) {
        const float4 yj = ytile[j];
        const float dot = x0 * yj.x + x1 * yj.y + x2 * yj.z;
        float r2 = fmaf(-2.0f, dot, xsq + yj.w);
        r2 = fmaxf(r2, 0.0f);
        const float f = 0.5f * r2 * __logf(fmaxf(r2, 1e-37f));
        const float* __restrict__ cj = &coeffs[(size_t)j * SOUT];
        #pragma unroll
        for (int s = 0; s < SOUT; ++s) acc[s] = fmaf(f, cj[s], acc[s]);
    }
    float4* o4 = (float4*)&out[(size_t)q * SOUT];
    #pragma unroll
    for (int s = 0; s < SOUT / 4; ++s)
        o4[s] = make_float4(acc[4 * s], acc[4 * s + 1], acc[4 * s + 2], acc[4 * s + 3]);
}

extern "C" void kernel_launch(void* const* d_in, const int* in_sizes, int n_in,
                              void* d_out, int out_size, void* d_ws, size_t ws_size,
                              hipStream_t stream) {
    const float* x      = (const float*)d_in[0];
    const float* y      = (const float*)d_in[1];
    const float* coeffs = (const float*)d_in[2];
    const float* shift  = (const float*)d_in[3];
    const float* scale  = (const float*)d_in[4];
    float* out = (float*)d_out;

    const size_t bt_bytes = (size_t)SOUT * KTOT * sizeof(_Float16);  // 532,480
    const size_t ye_bytes = (size_t)NC * 8 * sizeof(_Float16);       //  65,536

    if (ws_size >= bt_bytes + ye_bytes) {
        _Float16* bt = (_Float16*)d_ws;
        _Float16* yep = (_Float16*)((char*)d_ws + bt_bytes);
        hipLaunchKernelGGL(prep_bt, dim3((KTOT + 255) / 256, SOUT), dim3(256),
                           0, stream, coeffs, bt);
        hipLaunchKernelGGL(prep_ye, dim3((NC + 255) / 256), dim3(256),
                           0, stream, y, yep);
        hipLaunchKernelGGL(rbf_mfma3, dim3(NQ / BM), dim3(256), 0, stream,
                           x, yep, shift, scale, bt, out);
    } else {
        hipLaunchKernelGGL(rbf_tps_fallback, dim3(NQ / 256), dim3(256),
                           0, stream, x, y, coeffs, shift, scale, out);
    }
}